// Round 13
// baseline (338.966 us; speedup 1.0000x reference)
//
#include <hip/hip_runtime.h>
#include <hip/hip_bf16.h>

#define Bc 2
#define Tc 2048
#define Dc 1024
#define Hc 16
#define HDc 64

typedef __attribute__((ext_vector_type(4))) float f32x4;
typedef __attribute__((ext_vector_type(4))) short short4v;
typedef __attribute__((ext_vector_type(8))) short short8;
typedef __bf16 bf16x8 __attribute__((ext_vector_type(8)));

static __device__ __forceinline__ short f2bf(float f) {
  union { float f; unsigned u; } v; v.f = f;
  unsigned r = v.u + 0x7fffu + ((v.u >> 16) & 1u);  // RNE
  return (short)(r >> 16);
}

static __device__ __forceinline__ f32x4 mfma16(bf16x8 a, bf16x8 b, f32x4 c) {
  return __builtin_amdgcn_mfma_f32_16x16x32_bf16(a, b, c, 0, 0, 0);
}

// Convert wq,wk,wv (f32) -> bf16 Wb (3 x 1M elements)
__global__ __launch_bounds__(256) void wconv_kernel(
    const float* __restrict__ wq, const float* __restrict__ wk,
    const float* __restrict__ wv, short* __restrict__ Wb)
{
  const int z = blockIdx.y;
  const float* src = (z == 0) ? wq : (z == 1) ? wk : wv;
  const size_t i = ((size_t)blockIdx.x * 256 + threadIdx.x) * 8;
  const float4 a0 = *(const float4*)(src + i);
  const float4 a1 = *(const float4*)(src + i + 4);
  short8 r;
  r[0] = f2bf(a0.x); r[1] = f2bf(a0.y); r[2] = f2bf(a0.z); r[3] = f2bf(a0.w);
  r[4] = f2bf(a1.x); r[5] = f2bf(a1.y); r[6] = f2bf(a1.z); r[7] = f2bf(a1.w);
  *(short8*)(Wb + (size_t)z * 1048576 + i) = r;
}

// Fill rope table: tab[t*32+i] = {cos, sin}(pos[t] * 10000^(-i/32))
__global__ __launch_bounds__(256) void rope_tab_kernel(
    const int* __restrict__ tp, float2* __restrict__ tab)
{
  const int idx = blockIdx.x * 256 + threadIdx.x;   // 0 .. 65535
  const int t = idx >> 5, i = idx & 31;
  const float inv = expf((float)i * -0.2878231366242557f); // 10000^(-i/32)
  float sn, cs;
  sincosf((float)tp[t] * inv, &sn, &cs);
  tab[idx] = make_float2(cs, sn);
}

// Merged QKV GEMM. Q,K -> [bh][t][hd] with RoPE. V -> TRANSPOSED [bh][hd][t].
__global__ __launch_bounds__(256) void qkv_kernel(
    const float* __restrict__ x, const short* __restrict__ Wb,
    const float* __restrict__ bq, const float* __restrict__ bk,
    const float* __restrict__ bv, const float2* __restrict__ rtab,
    short* __restrict__ Qw, short* __restrict__ Kw, short* __restrict__ Vw)
{
  __shared__ short As[64][40];
  __shared__ short Bs[3][64][40];
  const int tid = threadIdx.x, lane = tid & 63, w = tid >> 6;
  const int wr = w >> 1, wc = w & 1;
  const int nbase = blockIdx.x * 64, mbase = blockIdx.y * 64;
  const int srow = tid >> 2, scol = (tid & 3) * 8;
  const int fr = lane & 15, fq = lane >> 4, kg = fq * 8;

  f32x4 acc[3][2][2] = {};

  for (int k0 = 0; k0 < Dc; k0 += 32) {
    if (k0) __syncthreads();
    {
      const float* src = x + (size_t)(mbase + srow) * Dc + k0 + scol;
      const float4 a0 = *(const float4*)src;
      const float4 a1 = *(const float4*)(src + 4);
      short* dst = &As[srow][scol];
      dst[0] = f2bf(a0.x); dst[1] = f2bf(a0.y); dst[2] = f2bf(a0.z); dst[3] = f2bf(a0.w);
      dst[4] = f2bf(a1.x); dst[5] = f2bf(a1.y); dst[6] = f2bf(a1.z); dst[7] = f2bf(a1.w);
    }
#pragma unroll
    for (int z = 0; z < 3; ++z)
      *(short8*)&Bs[z][srow][scol] =
          *(const short8*)(Wb + (size_t)z * 1048576 + (size_t)(nbase + srow) * Dc + k0 + scol);
    __syncthreads();
    const bf16x8 af0 = *(const bf16x8*)&As[wr * 32 + fr][kg];
    const bf16x8 af1 = *(const bf16x8*)&As[wr * 32 + 16 + fr][kg];
#pragma unroll
    for (int z = 0; z < 3; ++z) {
      const bf16x8 b0 = *(const bf16x8*)&Bs[z][wc * 32 + fr][kg];
      const bf16x8 b1 = *(const bf16x8*)&Bs[z][wc * 32 + 16 + fr][kg];
      acc[z][0][0] = mfma16(af0, b0, acc[z][0][0]);
      acc[z][0][1] = mfma16(af0, b1, acc[z][0][1]);
      acc[z][1][0] = mfma16(af1, b0, acc[z][1][0]);
      acc[z][1][1] = mfma16(af1, b1, acc[z][1][1]);
    }
  }

#pragma unroll
  for (int a2 = 0; a2 < 2; ++a2)
#pragma unroll
    for (int b2 = 0; b2 < 2; ++b2) {
      const int n = nbase + wc * 32 + b2 * 16 + fr;
      const float bi0 = bq[n], bi1 = bk[n], bi2 = bv[n];
      const int hd = n & 63, h = n >> 6;
      const int mb = mbase + wr * 32 + a2 * 16 + fq * 4;   // first of 4 rows
      const int tb = mb & (Tc - 1);
      const int bbi = mb >> 11;
      short4v pv;
#pragma unroll
      for (int r = 0; r < 4; ++r) {
        const int t = tb + r;
        const size_t oidx = (((size_t)bbi * Hc + h) * Tc + t) * HDc + hd;
        const float2 cs = rtab[t * 32 + (hd >> 1)];
        float v0 = acc[0][a2][b2][r] + bi0;
        float v1 = acc[1][a2][b2][r] + bi1;
        const float n0 = __shfl_xor(v0, 1);
        const float n1 = __shfl_xor(v1, 1);
        v0 = (hd & 1) ? (n0 * cs.y + v0 * cs.x) : (v0 * cs.x - n0 * cs.y);
        v1 = (hd & 1) ? (n1 * cs.y + v1 * cs.x) : (v1 * cs.x - n1 * cs.y);
        Qw[oidx] = f2bf(v0);
        Kw[oidx] = f2bf(v1);
        pv[r] = f2bf(acc[2][a2][b2][r] + bi2);
      }
      // V transposed: [bh][hd][t], 8B packed store (4 consecutive t)
      *(short4v*)(Vw + ((size_t)(bbi * Hc + h) * HDc + hd) * Tc + tb) = pv;
    }
}

// Output GEMM: out = Ob @ wo^T + bo. A bf16, B f32 (converted in staging).
__global__ __launch_bounds__(256) void out_kernel(
    const short* __restrict__ Ob, const float* __restrict__ wo,
    const float* __restrict__ bo, float* __restrict__ out)
{
  __shared__ short As[64][40];
  __shared__ short Bs[64][40];
  const int tid = threadIdx.x, lane = tid & 63, w = tid >> 6;
  const int wr = w >> 1, wc = w & 1;
  const int nbase = blockIdx.x * 64, mbase = blockIdx.y * 64;
  const int srow = tid >> 2, scol = (tid & 3) * 8;
  const int fr = lane & 15, fq = lane >> 4, kg = fq * 8;

  f32x4 acc[2][2] = {};

  for (int k0 = 0; k0 < Dc; k0 += 32) {
    if (k0) __syncthreads();
    *(short8*)&As[srow][scol] = *(const short8*)(Ob + (size_t)(mbase + srow) * Dc + k0 + scol);
    {
      const float* src = wo + (size_t)(nbase + srow) * Dc + k0 + scol;
      const float4 b0 = *(const float4*)src;
      const float4 b1 = *(const float4*)(src + 4);
      short* dst = &Bs[srow][scol];
      dst[0] = f2bf(b0.x); dst[1] = f2bf(b0.y); dst[2] = f2bf(b0.z); dst[3] = f2bf(b0.w);
      dst[4] = f2bf(b1.x); dst[5] = f2bf(b1.y); dst[6] = f2bf(b1.z); dst[7] = f2bf(b1.w);
    }
    __syncthreads();
    const bf16x8 af0 = *(const bf16x8*)&As[wr * 32 + fr][kg];
    const bf16x8 af1 = *(const bf16x8*)&As[wr * 32 + 16 + fr][kg];
    const bf16x8 b0 = *(const bf16x8*)&Bs[wc * 32 + fr][kg];
    const bf16x8 b1 = *(const bf16x8*)&Bs[wc * 32 + 16 + fr][kg];
    acc[0][0] = mfma16(af0, b0, acc[0][0]);
    acc[0][1] = mfma16(af0, b1, acc[0][1]);
    acc[1][0] = mfma16(af1, b0, acc[1][0]);
    acc[1][1] = mfma16(af1, b1, acc[1][1]);
  }

#pragma unroll
  for (int a2 = 0; a2 < 2; ++a2)
#pragma unroll
    for (int b2 = 0; b2 < 2; ++b2) {
      const int n = nbase + wc * 32 + b2 * 16 + fr;
      const float bv = bo[n];
#pragma unroll
      for (int r = 0; r < 4; ++r) {
        const int m = mbase + wr * 32 + a2 * 16 + fq * 4 + r;
        out[(size_t)m * Dc + n] = acc[a2][b2][r] + bv;
      }
    }
}

// Flash attention, causal. One wave per block (16 q-rows). K/V fragments
// loaded directly from global (L2-resident); NO barriers in the K-loop.
// Q,K: [bh][t][hd]; V: transposed [bh][hd][t]; Ps: wave-private LDS.
__global__ __launch_bounds__(64) void attn_kernel(
    const short* __restrict__ Qw, const short* __restrict__ Kw,
    const short* __restrict__ Vtg, short* __restrict__ Ob)
{
  __shared__ short Ps[16][72];
  const int lane = threadIdx.x;
  const int bh = blockIdx.y, bb = bh >> 4, h = bh & 15;
  const int qt = (int)gridDim.x - 1 - blockIdx.x;   // heavy blocks first
  const int q16 = qt * 16;
  const size_t baseQ = (size_t)bh * Tc * HDc;   // [t][hd]
  const size_t baseV = (size_t)bh * HDc * Tc;   // [hd][t]
  const int fr = lane & 15, fq = lane >> 4, kg = fq * 8;

  bf16x8 qf0, qf1;
  {
    const short* qrow = Qw + baseQ + (size_t)(q16 + fr) * HDc;
    qf0 = *(const bf16x8*)(qrow + kg);
    qf1 = *(const bf16x8*)(qrow + 32 + kg);
  }

  f32x4 o[4] = {};
  float mrun[4] = {-1e30f, -1e30f, -1e30f, -1e30f};
  float lrun[4] = {0.f, 0.f, 0.f, 0.f};

  const int ntiles = (qt >> 2) + 1;
  for (int kt = 0; kt < ntiles; ++kt) {
    const int kv0 = kt * 64;
    // QK^T: K fragments straight from global (L2)
    f32x4 s[4];
#pragma unroll
    for (int cf = 0; cf < 4; ++cf) {
      const short* kr = Kw + baseQ + (size_t)(kv0 + cf * 16 + fr) * HDc + kg;
      f32x4 acc = {};
      acc = mfma16(qf0, *(const bf16x8*)kr, acc);
      acc = mfma16(qf1, *(const bf16x8*)(kr + 32), acc);
      s[cf] = acc * 0.125f;
    }
    // V fragments (independent of softmax -> latency hidden under it)
    bf16x8 vb[2][4];
#pragma unroll
    for (int ks = 0; ks < 2; ++ks)
#pragma unroll
      for (int df = 0; df < 4; ++df)
        vb[ks][df] = *(const bf16x8*)(Vtg + baseV + (size_t)(df * 16 + fr) * Tc + kv0 + ks * 32 + kg);

    if (kt == ntiles - 1) {
#pragma unroll
      for (int cf = 0; cf < 4; ++cf) {
        const int col = kv0 + cf * 16 + fr;
#pragma unroll
        for (int r = 0; r < 4; ++r)
          if (col > q16 + fq * 4 + r) s[cf][r] = -1e30f;
      }
    }
    float pm[4];
#pragma unroll
    for (int r = 0; r < 4; ++r)
      pm[r] = fmaxf(fmaxf(s[0][r], s[1][r]), fmaxf(s[2][r], s[3][r]));
#pragma unroll
    for (int d = 1; d < 16; d <<= 1)
#pragma unroll
      for (int r = 0; r < 4; ++r)
        pm[r] = fmaxf(pm[r], __shfl_xor(pm[r], d));
    float alpha[4], rs[4];
#pragma unroll
    for (int r = 0; r < 4; ++r) {
      const float mn = fmaxf(mrun[r], pm[r]);
      alpha[r] = __expf(mrun[r] - mn);
      mrun[r] = mn;
      rs[r] = 0.f;
    }
#pragma unroll
    for (int cf = 0; cf < 4; ++cf)
#pragma unroll
      for (int r = 0; r < 4; ++r) {
        const float p = __expf(s[cf][r] - mrun[r]);
        s[cf][r] = p;
        rs[r] += p;
      }
#pragma unroll
    for (int d = 1; d < 16; d <<= 1)
#pragma unroll
      for (int r = 0; r < 4; ++r)
        rs[r] += __shfl_xor(rs[r], d);
#pragma unroll
    for (int r = 0; r < 4; ++r)
      lrun[r] = lrun[r] * alpha[r] + rs[r];
#pragma unroll
    for (int df = 0; df < 4; ++df)
#pragma unroll
      for (int r = 0; r < 4; ++r)
        o[df][r] *= alpha[r];
    // P -> wave-private LDS (transpose to A-fragment layout); no barrier:
    // same-wave write->read ordered by lgkmcnt (compiler-inserted).
#pragma unroll
    for (int cf = 0; cf < 4; ++cf)
#pragma unroll
      for (int r = 0; r < 4; ++r)
        Ps[fq * 4 + r][cf * 16 + fr] = f2bf(s[cf][r]);
#pragma unroll
    for (int ks = 0; ks < 2; ++ks) {
      const bf16x8 pa = *(const bf16x8*)&Ps[fr][ks * 32 + kg];
#pragma unroll
      for (int df = 0; df < 4; ++df)
        o[df] = mfma16(pa, vb[ks][df], o[df]);
    }
  }

#pragma unroll
  for (int df = 0; df < 4; ++df)
#pragma unroll
    for (int r = 0; r < 4; ++r) {
      const int t = q16 + fq * 4 + r;
      const float val = o[df][r] / lrun[r];
      Ob[((size_t)bb * Tc + t) * Dc + h * HDc + df * 16 + fr] = f2bf(val);
    }
}

extern "C" void kernel_launch(void* const* d_in, const int* in_sizes, int n_in,
                              void* d_out, int out_size, void* d_ws, size_t ws_size,
                              hipStream_t stream) {
  const float* x  = (const float*)d_in[0];
  const int*   tp = (const int*)d_in[1];
  const float* wq = (const float*)d_in[2];
  const float* bq = (const float*)d_in[3];
  const float* wk = (const float*)d_in[4];
  const float* bk = (const float*)d_in[5];
  const float* wv = (const float*)d_in[6];
  const float* bv = (const float*)d_in[7];
  const float* wo = (const float*)d_in[8];
  const float* bo = (const float*)d_in[9];
  float* out = (float*)d_out;

  char* ws = (char*)d_ws;
  short* Qw = (short*)(ws);                  // 8 MB
  short* Kw = (short*)(ws + (8u << 20));     // 8 MB
  short* Vw = (short*)(ws + (16u << 20));    // 8 MB (V^T: [bh][hd][t])
  short* Ob = (short*)(ws + (24u << 20));    // 8 MB, written by attn
  // Wb (6 MB) + rtab (512 KB) alias the Ob region: both dead before attn runs.
  short*  Wb   = (short*)(ws + (24u << 20));
  float2* rtab = (float2*)(ws + (30u << 20));

  dim3 blk(256);
  wconv_kernel<<<dim3(512, 3), blk, 0, stream>>>(wq, wk, wv, Wb);
  rope_tab_kernel<<<dim3(256), blk, 0, stream>>>(tp, rtab);
  qkv_kernel<<<dim3(16, 64), blk, 0, stream>>>(x, Wb, bq, bk, bv, rtab, Qw, Kw, Vw);
  attn_kernel<<<dim3(128, 32), dim3(64), 0, stream>>>(Qw, Kw, Vw, Ob);
  out_kernel<<<dim3(16, 64), blk, 0, stream>>>(Ob, wo, bo, out);
}

// Round 14
// 284.057 us; speedup vs baseline: 1.1933x; 1.1933x over previous
//
#include <hip/hip_runtime.h>
#include <hip/hip_bf16.h>

#define Bc 2
#define Tc 2048
#define Dc 1024
#define Hc 16
#define HDc 64

typedef __attribute__((ext_vector_type(4))) float f32x4;
typedef __attribute__((ext_vector_type(4))) short short4v;
typedef __attribute__((ext_vector_type(8))) short short8;
typedef __bf16 bf16x8 __attribute__((ext_vector_type(8)));

static __device__ __forceinline__ short f2bf(float f) {
  union { float f; unsigned u; } v; v.f = f;
  unsigned r = v.u + 0x7fffu + ((v.u >> 16) & 1u);  // RNE
  return (short)(r >> 16);
}

static __device__ __forceinline__ f32x4 mfma16(bf16x8 a, bf16x8 b, f32x4 c) {
  return __builtin_amdgcn_mfma_f32_16x16x32_bf16(a, b, c, 0, 0, 0);
}

// Convert wq,wk,wv (f32) -> bf16 Wb (3 x 1M elements)
__global__ __launch_bounds__(256) void wconv_kernel(
    const float* __restrict__ wq, const float* __restrict__ wk,
    const float* __restrict__ wv, short* __restrict__ Wb)
{
  const int z = blockIdx.y;
  const float* src = (z == 0) ? wq : (z == 1) ? wk : wv;
  const size_t i = ((size_t)blockIdx.x * 256 + threadIdx.x) * 8;
  const float4 a0 = *(const float4*)(src + i);
  const float4 a1 = *(const float4*)(src + i + 4);
  short8 r;
  r[0] = f2bf(a0.x); r[1] = f2bf(a0.y); r[2] = f2bf(a0.z); r[3] = f2bf(a0.w);
  r[4] = f2bf(a1.x); r[5] = f2bf(a1.y); r[6] = f2bf(a1.z); r[7] = f2bf(a1.w);
  *(short8*)(Wb + (size_t)z * 1048576 + i) = r;
}

// Fill rope table: tab[t*32+i] = {cos, sin}(pos[t] * 10000^(-i/32))
__global__ __launch_bounds__(256) void rope_tab_kernel(
    const int* __restrict__ tp, float2* __restrict__ tab)
{
  const int idx = blockIdx.x * 256 + threadIdx.x;   // 0 .. 65535
  const int t = idx >> 5, i = idx & 31;
  const float inv = expf((float)i * -0.2878231366242557f); // 10000^(-i/32)
  float sn, cs;
  sincosf((float)tp[t] * inv, &sn, &cs);
  tab[idx] = make_float2(cs, sn);
}

// Merged QKV GEMM. Q,K -> [bh][t][hd] with RoPE. V -> TRANSPOSED [bh][hd][t].
__global__ __launch_bounds__(256) void qkv_kernel(
    const float* __restrict__ x, const short* __restrict__ Wb,
    const float* __restrict__ bq, const float* __restrict__ bk,
    const float* __restrict__ bv, const float2* __restrict__ rtab,
    short* __restrict__ Qw, short* __restrict__ Kw, short* __restrict__ Vw)
{
  __shared__ short As[64][40];
  __shared__ short Bs[3][64][40];
  const int tid = threadIdx.x, lane = tid & 63, w = tid >> 6;
  const int wr = w >> 1, wc = w & 1;
  const int nbase = blockIdx.x * 64, mbase = blockIdx.y * 64;
  const int srow = tid >> 2, scol = (tid & 3) * 8;
  const int fr = lane & 15, fq = lane >> 4, kg = fq * 8;

  f32x4 acc[3][2][2] = {};

  for (int k0 = 0; k0 < Dc; k0 += 32) {
    if (k0) __syncthreads();
    {
      const float* src = x + (size_t)(mbase + srow) * Dc + k0 + scol;
      const float4 a0 = *(const float4*)src;
      const float4 a1 = *(const float4*)(src + 4);
      short* dst = &As[srow][scol];
      dst[0] = f2bf(a0.x); dst[1] = f2bf(a0.y); dst[2] = f2bf(a0.z); dst[3] = f2bf(a0.w);
      dst[4] = f2bf(a1.x); dst[5] = f2bf(a1.y); dst[6] = f2bf(a1.z); dst[7] = f2bf(a1.w);
    }
#pragma unroll
    for (int z = 0; z < 3; ++z)
      *(short8*)&Bs[z][srow][scol] =
          *(const short8*)(Wb + (size_t)z * 1048576 + (size_t)(nbase + srow) * Dc + k0 + scol);
    __syncthreads();
    const bf16x8 af0 = *(const bf16x8*)&As[wr * 32 + fr][kg];
    const bf16x8 af1 = *(const bf16x8*)&As[wr * 32 + 16 + fr][kg];
#pragma unroll
    for (int z = 0; z < 3; ++z) {
      const bf16x8 b0 = *(const bf16x8*)&Bs[z][wc * 32 + fr][kg];
      const bf16x8 b1 = *(const bf16x8*)&Bs[z][wc * 32 + 16 + fr][kg];
      acc[z][0][0] = mfma16(af0, b0, acc[z][0][0]);
      acc[z][0][1] = mfma16(af0, b1, acc[z][0][1]);
      acc[z][1][0] = mfma16(af1, b0, acc[z][1][0]);
      acc[z][1][1] = mfma16(af1, b1, acc[z][1][1]);
    }
  }

#pragma unroll
  for (int a2 = 0; a2 < 2; ++a2)
#pragma unroll
    for (int b2 = 0; b2 < 2; ++b2) {
      const int n = nbase + wc * 32 + b2 * 16 + fr;
      const float bi0 = bq[n], bi1 = bk[n], bi2 = bv[n];
      const int hd = n & 63, h = n >> 6;
      const int mb = mbase + wr * 32 + a2 * 16 + fq * 4;   // first of 4 rows
      const int tb = mb & (Tc - 1);
      const int bbi = mb >> 11;
      short4v pv;
#pragma unroll
      for (int r = 0; r < 4; ++r) {
        const int t = tb + r;
        const size_t oidx = (((size_t)bbi * Hc + h) * Tc + t) * HDc + hd;
        const float2 cs = rtab[t * 32 + (hd >> 1)];
        float v0 = acc[0][a2][b2][r] + bi0;
        float v1 = acc[1][a2][b2][r] + bi1;
        const float n0 = __shfl_xor(v0, 1);
        const float n1 = __shfl_xor(v1, 1);
        v0 = (hd & 1) ? (n0 * cs.y + v0 * cs.x) : (v0 * cs.x - n0 * cs.y);
        v1 = (hd & 1) ? (n1 * cs.y + v1 * cs.x) : (v1 * cs.x - n1 * cs.y);
        Qw[oidx] = f2bf(v0);
        Kw[oidx] = f2bf(v1);
        pv[r] = f2bf(acc[2][a2][b2][r] + bi2);
      }
      // V transposed: [bh][hd][t], 8B packed store (4 consecutive t)
      *(short4v*)(Vw + ((size_t)(bbi * Hc + h) * HDc + hd) * Tc + tb) = pv;
    }
}

// Output GEMM: out = Ob @ wo^T + bo. A bf16, B f32 (converted in staging).
__global__ __launch_bounds__(256) void out_kernel(
    const short* __restrict__ Ob, const float* __restrict__ wo,
    const float* __restrict__ bo, float* __restrict__ out)
{
  __shared__ short As[64][40];
  __shared__ short Bs[64][40];
  const int tid = threadIdx.x, lane = tid & 63, w = tid >> 6;
  const int wr = w >> 1, wc = w & 1;
  const int nbase = blockIdx.x * 64, mbase = blockIdx.y * 64;
  const int srow = tid >> 2, scol = (tid & 3) * 8;
  const int fr = lane & 15, fq = lane >> 4, kg = fq * 8;

  f32x4 acc[2][2] = {};

  for (int k0 = 0; k0 < Dc; k0 += 32) {
    if (k0) __syncthreads();
    *(short8*)&As[srow][scol] = *(const short8*)(Ob + (size_t)(mbase + srow) * Dc + k0 + scol);
    {
      const float* src = wo + (size_t)(nbase + srow) * Dc + k0 + scol;
      const float4 b0 = *(const float4*)src;
      const float4 b1 = *(const float4*)(src + 4);
      short* dst = &Bs[srow][scol];
      dst[0] = f2bf(b0.x); dst[1] = f2bf(b0.y); dst[2] = f2bf(b0.z); dst[3] = f2bf(b0.w);
      dst[4] = f2bf(b1.x); dst[5] = f2bf(b1.y); dst[6] = f2bf(b1.z); dst[7] = f2bf(b1.w);
    }
    __syncthreads();
    const bf16x8 af0 = *(const bf16x8*)&As[wr * 32 + fr][kg];
    const bf16x8 af1 = *(const bf16x8*)&As[wr * 32 + 16 + fr][kg];
    const bf16x8 b0 = *(const bf16x8*)&Bs[wc * 32 + fr][kg];
    const bf16x8 b1 = *(const bf16x8*)&Bs[wc * 32 + 16 + fr][kg];
    acc[0][0] = mfma16(af0, b0, acc[0][0]);
    acc[0][1] = mfma16(af0, b1, acc[0][1]);
    acc[1][0] = mfma16(af1, b0, acc[1][0]);
    acc[1][1] = mfma16(af1, b1, acc[1][1]);
  }

#pragma unroll
  for (int a2 = 0; a2 < 2; ++a2)
#pragma unroll
    for (int b2 = 0; b2 < 2; ++b2) {
      const int n = nbase + wc * 32 + b2 * 16 + fr;
      const float bv = bo[n];
#pragma unroll
      for (int r = 0; r < 4; ++r) {
        const int m = mbase + wr * 32 + a2 * 16 + fq * 4 + r;
        out[(size_t)m * Dc + n] = acc[a2][b2][r] + bv;
      }
    }
}

// Flash attention, causal. One wave per block, 32 q-rows per wave (two 16-row
// fragments over the SAME KV tile): halves tile count, shares K/V loads across
// fragments, and gives 2 independent softmax chains of ILP per wave.
__global__ __launch_bounds__(64) void attn_kernel(
    const short* __restrict__ Qw, const short* __restrict__ Kw,
    const short* __restrict__ Vtg, short* __restrict__ Ob)
{
  __shared__ short Ps[2][16][72];
  const int lane = threadIdx.x;
  const int bh = blockIdx.y, bb = bh >> 4, h = bh & 15;
  const int j = (int)gridDim.x - 1 - blockIdx.x;   // 32-row q-tile, heavy first
  const int q32 = j * 32;
  const size_t baseQ = (size_t)bh * Tc * HDc;   // [t][hd]
  const size_t baseV = (size_t)bh * HDc * Tc;   // [hd][t]
  const int fr = lane & 15, fq = lane >> 4, kg = fq * 8;

  bf16x8 qf[2][2];
#pragma unroll
  for (int f = 0; f < 2; ++f) {
    const short* qrow = Qw + baseQ + (size_t)(q32 + f * 16 + fr) * HDc;
    qf[f][0] = *(const bf16x8*)(qrow + kg);
    qf[f][1] = *(const bf16x8*)(qrow + 32 + kg);
  }

  f32x4 o[2][4] = {};
  float mrun[2][4], lrun[2][4];
#pragma unroll
  for (int f = 0; f < 2; ++f)
#pragma unroll
    for (int r = 0; r < 4; ++r) { mrun[f][r] = -1e30f; lrun[f][r] = 0.f; }

  const int ntiles = (j >> 1) + 1;
  for (int kt = 0; kt < ntiles; ++kt) {
    const int kv0 = kt * 64;
    // K fragments (shared by both q-fragments)
    bf16x8 ka[4][2];
#pragma unroll
    for (int cf = 0; cf < 4; ++cf) {
      const short* kr = Kw + baseQ + (size_t)(kv0 + cf * 16 + fr) * HDc + kg;
      ka[cf][0] = *(const bf16x8*)kr;
      ka[cf][1] = *(const bf16x8*)(kr + 32);
    }
    // V fragments, issued early (latency hides under QK + softmax)
    bf16x8 vb[2][4];
#pragma unroll
    for (int ks = 0; ks < 2; ++ks)
#pragma unroll
      for (int df = 0; df < 4; ++df)
        vb[ks][df] = *(const bf16x8*)(Vtg + baseV + (size_t)(df * 16 + fr) * Tc + kv0 + ks * 32 + kg);

    f32x4 s[2][4];
#pragma unroll
    for (int f = 0; f < 2; ++f)
#pragma unroll
      for (int cf = 0; cf < 4; ++cf) {
        f32x4 acc = {};
        acc = mfma16(qf[f][0], ka[cf][0], acc);
        acc = mfma16(qf[f][1], ka[cf][1], acc);
        s[f][cf] = acc * 0.125f;
      }

    if (kt == ntiles - 1) {
#pragma unroll
      for (int f = 0; f < 2; ++f)
#pragma unroll
        for (int cf = 0; cf < 4; ++cf) {
          const int col = kv0 + cf * 16 + fr;
#pragma unroll
          for (int r = 0; r < 4; ++r)
            if (col > q32 + f * 16 + fq * 4 + r) s[f][cf][r] = -1e30f;
        }
    }

    float pm[2][4], alpha[2][4], rs[2][4];
#pragma unroll
    for (int f = 0; f < 2; ++f)
#pragma unroll
      for (int r = 0; r < 4; ++r)
        pm[f][r] = fmaxf(fmaxf(s[f][0][r], s[f][1][r]), fmaxf(s[f][2][r], s[f][3][r]));
#pragma unroll
    for (int d = 1; d < 16; d <<= 1)   // two independent trees interleave
#pragma unroll
      for (int f = 0; f < 2; ++f)
#pragma unroll
        for (int r = 0; r < 4; ++r)
          pm[f][r] = fmaxf(pm[f][r], __shfl_xor(pm[f][r], d));
#pragma unroll
    for (int f = 0; f < 2; ++f)
#pragma unroll
      for (int r = 0; r < 4; ++r) {
        const float mn = fmaxf(mrun[f][r], pm[f][r]);
        alpha[f][r] = __expf(mrun[f][r] - mn);
        mrun[f][r] = mn;
        rs[f][r] = 0.f;
      }
#pragma unroll
    for (int f = 0; f < 2; ++f)
#pragma unroll
      for (int cf = 0; cf < 4; ++cf)
#pragma unroll
        for (int r = 0; r < 4; ++r) {
          const float p = __expf(s[f][cf][r] - mrun[f][r]);
          s[f][cf][r] = p;
          rs[f][r] += p;
        }
#pragma unroll
    for (int d = 1; d < 16; d <<= 1)
#pragma unroll
      for (int f = 0; f < 2; ++f)
#pragma unroll
        for (int r = 0; r < 4; ++r)
          rs[f][r] += __shfl_xor(rs[f][r], d);
#pragma unroll
    for (int f = 0; f < 2; ++f)
#pragma unroll
      for (int r = 0; r < 4; ++r)
        lrun[f][r] = lrun[f][r] * alpha[f][r] + rs[f][r];
#pragma unroll
    for (int f = 0; f < 2; ++f)
#pragma unroll
      for (int df = 0; df < 4; ++df)
#pragma unroll
        for (int r = 0; r < 4; ++r)
          o[f][df][r] *= alpha[f][r];
    // P -> wave-private LDS transpose (per fragment region); no barriers.
#pragma unroll
    for (int f = 0; f < 2; ++f)
#pragma unroll
      for (int cf = 0; cf < 4; ++cf)
#pragma unroll
        for (int r = 0; r < 4; ++r)
          Ps[f][fq * 4 + r][cf * 16 + fr] = f2bf(s[f][cf][r]);
#pragma unroll
    for (int f = 0; f < 2; ++f)
#pragma unroll
      for (int ks = 0; ks < 2; ++ks) {
        const bf16x8 pa = *(const bf16x8*)&Ps[f][fr][ks * 32 + kg];
#pragma unroll
        for (int df = 0; df < 4; ++df)
          o[f][df] = mfma16(pa, vb[ks][df], o[f][df]);
      }
  }

#pragma unroll
  for (int f = 0; f < 2; ++f)
#pragma unroll
    for (int df = 0; df < 4; ++df)
#pragma unroll
      for (int r = 0; r < 4; ++r) {
        const int t = q32 + f * 16 + fq * 4 + r;
        Ob[((size_t)bb * Tc + t) * Dc + h * HDc + df * 16 + fr] =
            f2bf(o[f][df][r] / lrun[f][r]);
      }
}

extern "C" void kernel_launch(void* const* d_in, const int* in_sizes, int n_in,
                              void* d_out, int out_size, void* d_ws, size_t ws_size,
                              hipStream_t stream) {
  const float* x  = (const float*)d_in[0];
  const int*   tp = (const int*)d_in[1];
  const float* wq = (const float*)d_in[2];
  const float* bq = (const float*)d_in[3];
  const float* wk = (const float*)d_in[4];
  const float* bk = (const float*)d_in[5];
  const float* wv = (const float*)d_in[6];
  const float* bv = (const float*)d_in[7];
  const float* wo = (const float*)d_in[8];
  const float* bo = (const float*)d_in[9];
  float* out = (float*)d_out;

  char* ws = (char*)d_ws;
  short* Qw = (short*)(ws);                  // 8 MB
  short* Kw = (short*)(ws + (8u << 20));     // 8 MB
  short* Vw = (short*)(ws + (16u << 20));    // 8 MB (V^T: [bh][hd][t])
  short* Ob = (short*)(ws + (24u << 20));    // 8 MB, written by attn
  // Wb (6 MB) + rtab (512 KB) alias the Ob region: both dead before attn runs.
  short*  Wb   = (short*)(ws + (24u << 20));
  float2* rtab = (float2*)(ws + (30u << 20));

  dim3 blk(256);
  wconv_kernel<<<dim3(512, 3), blk, 0, stream>>>(wq, wk, wv, Wb);
  rope_tab_kernel<<<dim3(256), blk, 0, stream>>>(tp, rtab);
  qkv_kernel<<<dim3(16, 64), blk, 0, stream>>>(x, Wb, bq, bk, bv, rtab, Qw, Kw, Vw);
  attn_kernel<<<dim3(64, 32), dim3(64), 0, stream>>>(Qw, Kw, Vw, Ob);
  out_kernel<<<dim3(16, 64), blk, 0, stream>>>(Ob, wo, bo, out);
}